// Round 8
// baseline (624.527 us; speedup 1.0000x reference)
//
#include <hip/hip_runtime.h>
#include <hip/hip_bf16.h>

typedef __hip_bfloat16 bf16;

#define N_NODES 100000
#define N_EDGES 1600000
#define IN_F    128
#define HH      3      // heads
#define DD      16     // out feats per head
#define HD      48     // HH*DD
#define NEG_SLOPE 0.2f
#define EPS_V   1e-9f

#define NB      391    // ceil(N_NODES / 256) buckets
#define BW_SH   8      // bucket = node >> 8 (256 nodes per bucket)
#define MS_T    8192   // edges per multisplit workgroup

__device__ __forceinline__ float leaky(float x) { return x >= 0.f ? x : NEG_SLOPE * x; }
__device__ __forceinline__ float b2f(bf16 x) { return __bfloat162float(x); }
__device__ __forceinline__ unsigned pkbf(float a, float b) {
    unsigned ua = (unsigned)__builtin_bit_cast(unsigned short, __float2bfloat16(a));
    unsigned ub = (unsigned)__builtin_bit_cast(unsigned short, __float2bfloat16(b));
    return ua | (ub << 16);
}

// ------- GEMM: one row per thread; ft16 stored head-sliced [H][N][16] -------
__global__ __launch_bounds__(256) void k_gemm(const float* __restrict__ feat,
                                              const float* __restrict__ W,
                                              float* __restrict__ ft,
                                              bf16* __restrict__ ft16) {
    int row = blockIdx.x * 256 + threadIdx.x;
    if (row >= N_NODES) return;
    float acc[HD];
#pragma unroll
    for (int c = 0; c < HD; ++c) acc[c] = 0.f;
    const float4* frow = (const float4*)(feat + (size_t)row * IN_F);
    for (int k4 = 0; k4 < IN_F / 4; ++k4) {
        float4 f = frow[k4];
        int k = k4 * 4;
#pragma unroll
        for (int c = 0; c < HD; ++c) acc[c] += f.x * W[(k + 0) * HD + c];
#pragma unroll
        for (int c = 0; c < HD; ++c) acc[c] += f.y * W[(k + 1) * HD + c];
#pragma unroll
        for (int c = 0; c < HD; ++c) acc[c] += f.z * W[(k + 2) * HD + c];
#pragma unroll
        for (int c = 0; c < HD; ++c) acc[c] += f.w * W[(k + 3) * HD + c];
    }
    float4* orow = (float4*)(ft + (size_t)row * HD);
#pragma unroll
    for (int c = 0; c < HD / 4; ++c)
        orow[c] = make_float4(acc[4 * c], acc[4 * c + 1], acc[4 * c + 2], acc[4 * c + 3]);
#pragma unroll
    for (int hh = 0; hh < HH; ++hh) {
        uint4 w0, w1;
        w0.x = pkbf(acc[hh * 16 + 0], acc[hh * 16 + 1]);
        w0.y = pkbf(acc[hh * 16 + 2], acc[hh * 16 + 3]);
        w0.z = pkbf(acc[hh * 16 + 4], acc[hh * 16 + 5]);
        w0.w = pkbf(acc[hh * 16 + 6], acc[hh * 16 + 7]);
        w1.x = pkbf(acc[hh * 16 + 8], acc[hh * 16 + 9]);
        w1.y = pkbf(acc[hh * 16 + 10], acc[hh * 16 + 11]);
        w1.z = pkbf(acc[hh * 16 + 12], acc[hh * 16 + 13]);
        w1.w = pkbf(acc[hh * 16 + 14], acc[hh * 16 + 15]);
        uint4* o = (uint4*)(ft16 + ((size_t)hh * N_NODES + row) * 16);
        o[0] = w0;
        o[1] = w1;
    }
}

// ---------------- el/er ----------------
__global__ void k_eler(const float* __restrict__ ft, const float* __restrict__ attn_l,
                       const float* __restrict__ attn_r, float* __restrict__ el,
                       float* __restrict__ er) {
    int i = blockIdx.x * blockDim.x + threadIdx.x;
    if (i >= N_NODES * HH) return;
    int h = i % HH;
    float sl = 0.f, sr = 0.f;
#pragma unroll
    for (int d = 0; d < DD; ++d) {
        float v = ft[i * DD + d];
        sl += v * attn_l[h * DD + d];
        sr += v * attn_r[h * DD + d];
    }
    el[i] = sl;
    er[i] = sr;
}

// ---------------- K1: per-bucket histograms (LDS-privatized, int4 loads) -------------
__global__ __launch_bounds__(256) void k_bhist(const int4* __restrict__ src4,
                                               const int4* __restrict__ dst4,
                                               int* __restrict__ bcnt_s,
                                               int* __restrict__ bcnt_d) {
    __shared__ int ls[NB], ld_[NB];
    int t = threadIdx.x;
    for (int i = t; i < NB; i += 256) { ls[i] = 0; ld_[i] = 0; }
    __syncthreads();
    const int NE4 = N_EDGES / 4;
    for (int e = blockIdx.x * 256 + t; e < NE4; e += gridDim.x * 256) {
        int4 d = dst4[e];
        atomicAdd(&ld_[d.x >> BW_SH], 1);
        atomicAdd(&ld_[d.y >> BW_SH], 1);
        atomicAdd(&ld_[d.z >> BW_SH], 1);
        atomicAdd(&ld_[d.w >> BW_SH], 1);
        int4 s = src4[e];
        atomicAdd(&ls[s.x >> BW_SH], 1);
        atomicAdd(&ls[s.y >> BW_SH], 1);
        atomicAdd(&ls[s.z >> BW_SH], 1);
        atomicAdd(&ls[s.w >> BW_SH], 1);
    }
    __syncthreads();
    for (int i = t; i < NB; i += 256) {
        if (ld_[i]) atomicAdd(&bcnt_d[i], ld_[i]);
        if (ls[i]) atomicAdd(&bcnt_s[i], ls[i]);
    }
}

// ---------------- K2: scan bucket counts -> bucket bases (+ sentinels) -------------
__global__ __launch_bounds__(512) void k_bscan(const int* __restrict__ bcnt_d,
                                               int* __restrict__ bbase_d,
                                               const int* __restrict__ bcnt_s,
                                               int* __restrict__ bbase_s,
                                               int* __restrict__ rows_d,
                                               int* __restrict__ rows_s) {
    __shared__ int buf[512];
    const int* c = blockIdx.x ? bcnt_s : bcnt_d;
    int* o = blockIdx.x ? bbase_s : bbase_d;
    int t = threadIdx.x;
    int v = (t < NB) ? c[t] : 0;
    buf[t] = v;
    __syncthreads();
    for (int off = 1; off < 512; off <<= 1) {
        int u = (t >= off) ? buf[t - off] : 0;
        __syncthreads();
        buf[t] += u;
        __syncthreads();
    }
    if (t < NB) o[t] = buf[t] - v;      // exclusive
    if (t == NB - 1) o[NB] = buf[t];    // == N_EDGES
    if (t == 0) {
        if (blockIdx.x) rows_s[N_NODES] = N_EDGES;
        else            rows_d[N_NODES] = N_EDGES;
    }
}

// ---------------- K3: multisplit — bucket edges for both directions ----------------
__global__ __launch_bounds__(256) void k_msplit(const int* __restrict__ src,
                                                const int* __restrict__ dst,
                                                const int* __restrict__ bbase_d,
                                                const int* __restrict__ bbase_s,
                                                int* __restrict__ bfill_d,
                                                int* __restrict__ bfill_s,
                                                unsigned* __restrict__ bkt_d,
                                                unsigned* __restrict__ bkt_s) {
    __shared__ int lcD[NB], lcS[NB], wbD[NB], wbS[NB], rkD[NB], rkS[NB];
    int t = threadIdx.x;
    int e0 = blockIdx.x * MS_T;
    int e1 = min(e0 + MS_T, N_EDGES);
    for (int i = t; i < NB; i += 256) { lcD[i] = 0; lcS[i] = 0; rkD[i] = 0; rkS[i] = 0; }
    __syncthreads();
    for (int e = e0 + t; e < e1; e += 256) {
        atomicAdd(&lcD[dst[e] >> BW_SH], 1);
        atomicAdd(&lcS[src[e] >> BW_SH], 1);
    }
    __syncthreads();
    for (int i = t; i < NB; i += 256) {
        wbD[i] = bbase_d[i] + (lcD[i] ? atomicAdd(&bfill_d[i], lcD[i]) : 0);
        wbS[i] = bbase_s[i] + (lcS[i] ? atomicAdd(&bfill_s[i], lcS[i]) : 0);
    }
    __syncthreads();
    for (int e = e0 + t; e < e1; e += 256) {
        int s = src[e], d = dst[e];
        int bd = d >> BW_SH, bs = s >> BW_SH;
        int rd = atomicAdd(&rkD[bd], 1);
        int rs = atomicAdd(&rkS[bs], 1);
        bkt_d[wbD[bd] + rd] = (unsigned)s | ((unsigned)(d & 255) << 17);
        bkt_s[wbS[bs] + rs] = (unsigned)d | ((unsigned)(s & 255) << 17);
    }
}

// ---------------- K4: per-bucket CSR finalize (rows + payload scatter) --------------
__global__ __launch_bounds__(256) void k_bfinal(const unsigned* __restrict__ bkt,
                                                const int* __restrict__ bbase,
                                                int* __restrict__ rows,
                                                int* __restrict__ outarr) {
    __shared__ int cnt[256], pre[256], rnk[256], wsum[4];
    int b = blockIdx.x, t = threadIdx.x;
    int base = bbase[b], end = bbase[b + 1];
    cnt[t] = 0; rnk[t] = 0;
    __syncthreads();
    for (int i = base + t; i < end; i += 256)
        atomicAdd(&cnt[(bkt[i] >> 17) & 255], 1);
    __syncthreads();
    int lane = t & 63, w = t >> 6;
    int v = cnt[t];
    int sc = v;
#pragma unroll
    for (int off = 1; off < 64; off <<= 1) {
        int u = __shfl_up(sc, off, 64);
        if (lane >= off) sc += u;
    }
    if (lane == 63) wsum[w] = sc;
    __syncthreads();
    int wpre = 0;
    for (int j = 0; j < w; ++j) wpre += wsum[j];
    int excl = wpre + sc - v;
    pre[t] = excl;
    int n = (b << BW_SH) + t;
    if (n < N_NODES) rows[n] = base + excl;
    __syncthreads();
    for (int i = base + t; i < end; i += 256) {
        unsigned u = bkt[i];
        int loc = (u >> 17) & 255;
        int r = atomicAdd(&rnk[loc], 1);
        outarr[base + pre[loc] + r] = (int)(u & 0x1FFFFu);
    }
}

// -------- src-side segment softmax stats: per-node (max, sum) only ----------
__global__ __launch_bounds__(256) void k_seg_src(const int* __restrict__ dsts_s,
                                                 const int* __restrict__ rows_s,
                                                 const float* __restrict__ el,
                                                 const float* __restrict__ er,
                                                 float2* __restrict__ mssrc) {
    int wid = threadIdx.x >> 6, lane = threadIdx.x & 63;
    int n = blockIdx.x * 4 + wid;
    if (n >= N_NODES) return;
    int rs = rows_s[n], re = rows_s[n + 1];
    if (rs >= re) return;
    float el0 = el[n * 3 + 0], el1 = el[n * 3 + 1], el2 = el[n * 3 + 2];
    bool single = (re - rs) <= 64;
    float m0 = -INFINITY, m1 = -INFINITY, m2 = -INFINITY;
    float c0 = -INFINITY, c1 = -INFINITY, c2 = -INFINITY;
    for (int p0 = rs; p0 < re; p0 += 64) {
        int p = p0 + lane;
        bool act = p < re;
        int d = act ? dsts_s[p] : 0;
        float t0 = act ? leaky(el0 + er[d * 3 + 0]) : -INFINITY;
        float t1 = act ? leaky(el1 + er[d * 3 + 1]) : -INFINITY;
        float t2 = act ? leaky(el2 + er[d * 3 + 2]) : -INFINITY;
        if (single) { c0 = t0; c1 = t1; c2 = t2; }
        m0 = fmaxf(m0, t0); m1 = fmaxf(m1, t1); m2 = fmaxf(m2, t2);
    }
#pragma unroll
    for (int off = 1; off < 64; off <<= 1) {
        m0 = fmaxf(m0, __shfl_xor(m0, off));
        m1 = fmaxf(m1, __shfl_xor(m1, off));
        m2 = fmaxf(m2, __shfl_xor(m2, off));
    }
    float s0 = 0, s1 = 0, s2 = 0;
    if (single) {
        bool act = (rs + lane) < re;
        s0 = act ? expf(c0 - m0) : 0.f;
        s1 = act ? expf(c1 - m1) : 0.f;
        s2 = act ? expf(c2 - m2) : 0.f;
    } else {
        for (int p0 = rs; p0 < re; p0 += 64) {
            int p = p0 + lane;
            if (p < re) {
                int d = dsts_s[p];
                s0 += expf(leaky(el0 + er[d * 3 + 0]) - m0);
                s1 += expf(leaky(el1 + er[d * 3 + 1]) - m1);
                s2 += expf(leaky(el2 + er[d * 3 + 2]) - m2);
            }
        }
    }
#pragma unroll
    for (int off = 1; off < 64; off <<= 1) {
        s0 += __shfl_xor(s0, off);
        s1 += __shfl_xor(s1, off);
        s2 += __shfl_xor(s2, off);
    }
    if (lane == 0) {
        mssrc[n * 3 + 0] = make_float2(m0, s0);
        mssrc[n * 3 + 1] = make_float2(m1, s1);
        mssrc[n * 3 + 2] = make_float2(m2, s2);
    }
}

// -------- dst-side stats + fused symmetric attention; a stored head-major [H][E] -----
__global__ __launch_bounds__(256) void k_seg_dst_attn(const int* __restrict__ srcs_d,
                                                      const int* __restrict__ rows_d,
                                                      const float* __restrict__ el,
                                                      const float* __restrict__ er,
                                                      const float2* __restrict__ mssrc,
                                                      float* __restrict__ a_h) {
    int wid = threadIdx.x >> 6, lane = threadIdx.x & 63;
    int n = blockIdx.x * 4 + wid;
    if (n >= N_NODES) return;
    int rs = rows_d[n], re = rows_d[n + 1];
    if (rs >= re) return;
    float er0 = er[n * 3 + 0], er1 = er[n * 3 + 1], er2 = er[n * 3 + 2];
    bool single = (re - rs) <= 64;
    float m0 = -INFINITY, m1 = -INFINITY, m2 = -INFINITY;
    float c0 = -INFINITY, c1 = -INFINITY, c2 = -INFINITY;
    int scache = 0;
    for (int p0 = rs; p0 < re; p0 += 64) {
        int p = p0 + lane;
        bool act = p < re;
        int s = act ? srcs_d[p] : 0;
        if (single) scache = s;
        float t0 = act ? leaky(el[s * 3 + 0] + er0) : -INFINITY;
        float t1 = act ? leaky(el[s * 3 + 1] + er1) : -INFINITY;
        float t2 = act ? leaky(el[s * 3 + 2] + er2) : -INFINITY;
        if (single) { c0 = t0; c1 = t1; c2 = t2; }
        m0 = fmaxf(m0, t0); m1 = fmaxf(m1, t1); m2 = fmaxf(m2, t2);
    }
#pragma unroll
    for (int off = 1; off < 64; off <<= 1) {
        m0 = fmaxf(m0, __shfl_xor(m0, off));
        m1 = fmaxf(m1, __shfl_xor(m1, off));
        m2 = fmaxf(m2, __shfl_xor(m2, off));
    }
    float s0 = 0, s1 = 0, s2 = 0;
    if (single) {
        bool act = (rs + lane) < re;
        s0 = act ? expf(c0 - m0) : 0.f;
        s1 = act ? expf(c1 - m1) : 0.f;
        s2 = act ? expf(c2 - m2) : 0.f;
    } else {
        for (int p0 = rs; p0 < re; p0 += 64) {
            int p = p0 + lane;
            if (p < re) {
                int s = srcs_d[p];
                s0 += expf(leaky(el[s * 3 + 0] + er0) - m0);
                s1 += expf(leaky(el[s * 3 + 1] + er1) - m1);
                s2 += expf(leaky(el[s * 3 + 2] + er2) - m2);
            }
        }
    }
#pragma unroll
    for (int off = 1; off < 64; off <<= 1) {
        s0 += __shfl_xor(s0, off);
        s1 += __shfl_xor(s1, off);
        s2 += __shfl_xor(s2, off);
    }
    float i0 = 1.f / s0, i1 = 1.f / s1, i2 = 1.f / s2;
    for (int p0 = rs; p0 < re; p0 += 64) {
        int p = p0 + lane;
        if (p >= re) break;
        int s = single ? scache : srcs_d[p];
        float t0, t1, t2;
        if (single) { t0 = c0; t1 = c1; t2 = c2; }
        else {
            t0 = leaky(el[s * 3 + 0] + er0);
            t1 = leaky(el[s * 3 + 1] + er1);
            t2 = leaky(el[s * 3 + 2] + er2);
        }
        float2 a0 = mssrc[s * 3 + 0], a1 = mssrc[s * 3 + 1], a2 = mssrc[s * 3 + 2];
        float d0 = fmaxf(expf(t0 - m0) * i0, EPS_V);
        float d1 = fmaxf(expf(t1 - m1) * i1, EPS_V);
        float d2 = fmaxf(expf(t2 - m2) * i2, EPS_V);
        float u0 = fmaxf(expf(t0 - a0.x) / a0.y, EPS_V);
        float u1 = fmaxf(expf(t1 - a1.x) / a1.y, EPS_V);
        float u2 = fmaxf(expf(t2 - a2.x) / a2.y, EPS_V);
        a_h[0 * N_EDGES + p] = sqrtf(d0 * u0);
        a_h[1 * N_EDGES + p] = sqrtf(d1 * u1);
        a_h[2 * N_EDGES + p] = sqrtf(d2 * u2);
    }
}

// ------- hop: thread per (head,node); head-sliced [H][N][16] bf16; 8-deep pipeline ----
__global__ __launch_bounds__(256) void k_hop(const bf16* __restrict__ cur,
                                             const float* __restrict__ a_h,
                                             const int* __restrict__ rows_d,
                                             const int* __restrict__ srcs_d,
                                             bf16* __restrict__ out) {
    int i = blockIdx.x * 256 + threadIdx.x;   // i = h*N + n (head-major grid)
    if (i >= HH * N_NODES) return;
    int h = i / N_NODES;
    int n = i - h * N_NODES;
    int rs = rows_d[n], re = rows_d[n + 1];
    const float* ah = a_h + (size_t)h * N_EDGES;
    const bf16* curh = cur + (size_t)h * N_NODES * 16;
    float acc[16];
#pragma unroll
    for (int d = 0; d < 16; ++d) acc[d] = 0.f;
    for (int p = rs; p < re; p += 8) {
        int cnt = re - p;
        int s[8];
        float a[8];
#pragma unroll
        for (int j = 0; j < 8; ++j) s[j] = (j < cnt) ? srcs_d[p + j] : 0;
#pragma unroll
        for (int j = 0; j < 8; ++j) a[j] = (j < cnt) ? ah[p + j] : 0.f;
        uint4 g0[8], g1[8];
#pragma unroll
        for (int j = 0; j < 8; ++j) {
            const uint4* cp = (const uint4*)(curh + (size_t)s[j] * 16);
            g0[j] = cp[0];
            g1[j] = cp[1];
        }
#pragma unroll
        for (int j = 0; j < 8; ++j) {
            unsigned u;
            u = g0[j].x; acc[0]  += a[j] * __uint_as_float(u << 16);
                         acc[1]  += a[j] * __uint_as_float(u & 0xffff0000u);
            u = g0[j].y; acc[2]  += a[j] * __uint_as_float(u << 16);
                         acc[3]  += a[j] * __uint_as_float(u & 0xffff0000u);
            u = g0[j].z; acc[4]  += a[j] * __uint_as_float(u << 16);
                         acc[5]  += a[j] * __uint_as_float(u & 0xffff0000u);
            u = g0[j].w; acc[6]  += a[j] * __uint_as_float(u << 16);
                         acc[7]  += a[j] * __uint_as_float(u & 0xffff0000u);
            u = g1[j].x; acc[8]  += a[j] * __uint_as_float(u << 16);
                         acc[9]  += a[j] * __uint_as_float(u & 0xffff0000u);
            u = g1[j].y; acc[10] += a[j] * __uint_as_float(u << 16);
                         acc[11] += a[j] * __uint_as_float(u & 0xffff0000u);
            u = g1[j].z; acc[12] += a[j] * __uint_as_float(u << 16);
                         acc[13] += a[j] * __uint_as_float(u & 0xffff0000u);
            u = g1[j].w; acc[14] += a[j] * __uint_as_float(u << 16);
                         acc[15] += a[j] * __uint_as_float(u & 0xffff0000u);
        }
    }
    uint4 w0, w1;
    w0.x = pkbf(acc[0], acc[1]);   w0.y = pkbf(acc[2], acc[3]);
    w0.z = pkbf(acc[4], acc[5]);   w0.w = pkbf(acc[6], acc[7]);
    w1.x = pkbf(acc[8], acc[9]);   w1.y = pkbf(acc[10], acc[11]);
    w1.z = pkbf(acc[12], acc[13]); w1.w = pkbf(acc[14], acc[15]);
    uint4* o = (uint4*)(out + (size_t)i * 16);
    o[0] = w0;
    o[1] = w1;
}

// ---------------- feat_trans + hop attention + output ----------------
__global__ void k_final(const float* __restrict__ ft, const bf16* __restrict__ cur1,
                        const bf16* __restrict__ cur2, const bf16* __restrict__ cur3,
                        const float* __restrict__ hop_l, const float* __restrict__ hop_r,
                        const float* __restrict__ pos_emb, const float* __restrict__ scales,
                        const float* __restrict__ offs, const float* __restrict__ bias,
                        float* __restrict__ out) {
    int i = blockIdx.x * blockDim.x + threadIdx.x;  // i = n*3+h
    if (i >= N_NODES * HH) return;
    int h = i % HH;
    int n = i / HH;
    size_t sl = ((size_t)h * N_NODES + n) * 16;     // head-sliced offset for cur*
    float hk[4][DD];
#pragma unroll
    for (int k = 0; k < 4; ++k) {
        float x[DD];
#pragma unroll
        for (int d = 0; d < DD; ++d) {
            x[d] = (k == 0) ? ft[(size_t)i * DD + d]
                 : (k == 1) ? b2f(cur1[sl + d])
                 : (k == 2) ? b2f(cur2[sl + d])
                            : b2f(cur3[sl + d]);
        }
        float m = 0.f;
#pragma unroll
        for (int d = 0; d < DD; ++d) m += x[d];
        m *= (1.f / DD);
        float v2 = 0.f;
#pragma unroll
        for (int d = 0; d < DD; ++d) {
            float c = x[d] - m;
            v2 += c * c;
        }
        v2 = v2 * (1.f / DD) + EPS_V;
        float rsq = rsqrtf(v2);
#pragma unroll
        for (int d = 0; d < DD; ++d) {
            hk[k][d] = (x[d] - m) * scales[k * HD + h * DD + d] * rsq +
                       offs[k * HD + h * DD + d] + pos_emb[h * 64 + k * DD + d];
        }
    }
    float al = 0.f;
#pragma unroll
    for (int d = 0; d < DD; ++d) al += hk[0][d] * hop_l[h * DD + d];
    float ar[3], mx = -1e30f;
#pragma unroll
    for (int k = 0; k < 3; ++k) {
        float s = 0.f;
#pragma unroll
        for (int d = 0; d < DD; ++d) s += hk[k + 1][d] * hop_r[h * DD + d];
        ar[k] = leaky(s + al);
        mx = fmaxf(mx, ar[k]);
    }
    float den = 0.f, wgt[3];
#pragma unroll
    for (int k = 0; k < 3; ++k) {
        wgt[k] = expf(ar[k] - mx);
        den += wgt[k];
    }
#pragma unroll
    for (int k = 0; k < 3; ++k) wgt[k] /= den;
#pragma unroll
    for (int d = 0; d < DD; ++d) {
        float o = hk[1][d] * wgt[0] + hk[2][d] * wgt[1] + hk[3][d] * wgt[2] +
                  bias[h * DD + d];
        out[i * DD + d] = o;
    }
}

// ---------------- workspace layout (4B-element offsets) ----------------
#define OFF_FT     0u          // 4.8M f32
#define OFF_FT16   4800000u    // 2.4M slots (bf16 [3][N][16])
#define OFF_EL     7200000u    // 300k
#define OFF_ER     7500000u    // 300k
#define OFF_MSSRC  7800000u    // 600k (float2 x 300k)
#define OFF_BCNT   8400000u    // 1600 [memset]
#define OFF_BBASE  8401600u    // 800
#define OFF_ROWD   8402400u    // 100001
#define OFF_ROWS_  8502402u    // 100001
#define OFF_BKTD   8602404u    // 1.6M u32
#define OFF_BKTS   10202404u   // 1.6M u32
#define OFF_SRCSD  11802404u   // 1.6M
#define OFF_DSTSS  13402404u   // 1.6M
#define OFF_ASORT  15002404u   // 4.8M ([3][E] head-major)
#define OFF_CUR1   19802404u   // 2.4M slots (bf16 [3][N][16])
#define OFF_CUR2   22202404u
#define OFF_CUR3   24602404u
#define WS_FLOATS  27002404u   // ~108 MB

extern "C" void kernel_launch(void* const* d_in, const int* in_sizes, int n_in,
                              void* d_out, int out_size, void* d_ws, size_t ws_size,
                              hipStream_t stream) {
    if (ws_size < (size_t)WS_FLOATS * 4) return;

    const float* feat   = (const float*)d_in[0];
    const int*   src    = (const int*)d_in[1];
    const int*   dst    = (const int*)d_in[2];
    const float* fc_W   = (const float*)d_in[3];
    const float* attn_l = (const float*)d_in[4];
    const float* attn_r = (const float*)d_in[5];
    const float* hop_l  = (const float*)d_in[6];
    const float* hop_r  = (const float*)d_in[7];
    const float* pos    = (const float*)d_in[8];
    const float* scal   = (const float*)d_in[9];
    const float* offs   = (const float*)d_in[10];
    const float* bias   = (const float*)d_in[11];
    float* out = (float*)d_out;

    float* ws = (float*)d_ws;
    float*    ft      = ws + OFF_FT;
    bf16*     ft16    = (bf16*)(ws + OFF_FT16);
    float*    el      = ws + OFF_EL;
    float*    er      = ws + OFF_ER;
    float2*   mssrc   = (float2*)(ws + OFF_MSSRC);
    int*      bcnt_d  = (int*)(ws + OFF_BCNT);
    int*      bcnt_s  = bcnt_d + 400;
    int*      bfill_d = bcnt_d + 800;
    int*      bfill_s = bcnt_d + 1200;
    int*      bbase_d = (int*)(ws + OFF_BBASE);
    int*      bbase_s = bbase_d + 400;
    int*      rows_d  = (int*)(ws + OFF_ROWD);
    int*      rows_s  = (int*)(ws + OFF_ROWS_);
    unsigned* bkt_d   = (unsigned*)(ws + OFF_BKTD);
    unsigned* bkt_s   = (unsigned*)(ws + OFF_BKTS);
    int*      srcs_d  = (int*)(ws + OFF_SRCSD);
    int*      dsts_s  = (int*)(ws + OFF_DSTSS);
    float*    a_h     = ws + OFF_ASORT;
    bf16*     cur1    = (bf16*)(ws + OFF_CUR1);
    bf16*     cur2    = (bf16*)(ws + OFF_CUR2);
    bf16*     cur3    = (bf16*)(ws + OFF_CUR3);

    hipMemsetAsync(ws + OFF_BCNT, 0, 1600 * 4, stream);

    k_gemm<<<(N_NODES + 255) / 256, 256, 0, stream>>>(feat, fc_W, ft, ft16);
    k_eler<<<(N_NODES * HH + 255) / 256, 256, 0, stream>>>(ft, attn_l, attn_r, el, er);

    k_bhist<<<400, 256, 0, stream>>>((const int4*)src, (const int4*)dst, bcnt_s, bcnt_d);
    k_bscan<<<2, 512, 0, stream>>>(bcnt_d, bbase_d, bcnt_s, bbase_s, rows_d, rows_s);
    k_msplit<<<(N_EDGES + MS_T - 1) / MS_T, 256, 0, stream>>>(src, dst, bbase_d, bbase_s,
                                                              bfill_d, bfill_s, bkt_d, bkt_s);
    k_bfinal<<<NB, 256, 0, stream>>>(bkt_d, bbase_d, rows_d, srcs_d);
    k_bfinal<<<NB, 256, 0, stream>>>(bkt_s, bbase_s, rows_s, dsts_s);

    k_seg_src<<<(N_NODES + 3) / 4, 256, 0, stream>>>(dsts_s, rows_s, el, er, mssrc);
    k_seg_dst_attn<<<(N_NODES + 3) / 4, 256, 0, stream>>>(srcs_d, rows_d, el, er,
                                                          mssrc, a_h);
    const int HOPG = (HH * N_NODES + 255) / 256;
    k_hop<<<HOPG, 256, 0, stream>>>(ft16, a_h, rows_d, srcs_d, cur1);
    k_hop<<<HOPG, 256, 0, stream>>>(cur1, a_h, rows_d, srcs_d, cur2);
    k_hop<<<HOPG, 256, 0, stream>>>(cur2, a_h, rows_d, srcs_d, cur3);
    k_final<<<(N_NODES * HH + 255) / 256, 256, 0, stream>>>(ft, cur1, cur2, cur3, hop_l,
                                                            hop_r, pos, scal, offs, bias,
                                                            out);
}

// Round 9
// 539.110 us; speedup vs baseline: 1.1584x; 1.1584x over previous
//
#include <hip/hip_runtime.h>
#include <hip/hip_bf16.h>

typedef __hip_bfloat16 bf16;

#define N_NODES 100000
#define N_EDGES 1600000
#define IN_F    128
#define HH      3      // heads
#define DD      16     // out feats per head
#define HD      48     // HH*DD
#define RP      64     // padded row length (bf16) = 128 B = 1 cache line
#define NEG_SLOPE 0.2f
#define EPS_V   1e-9f

#define NB      391    // ceil(N_NODES / 256) buckets
#define BW_SH   8      // bucket = node >> 8 (256 nodes per bucket)
#define MS_T    8192   // edges per multisplit workgroup

__device__ __forceinline__ float leaky(float x) { return x >= 0.f ? x : NEG_SLOPE * x; }
__device__ __forceinline__ float b2f(bf16 x) { return __bfloat162float(x); }
__device__ __forceinline__ unsigned short bfbits(float x) {
    return __builtin_bit_cast(unsigned short, __float2bfloat16(x));
}
__device__ __forceinline__ unsigned pkbf(float a, float b) {
    return (unsigned)bfbits(a) | ((unsigned)bfbits(b) << 16);
}

// ------- GEMM: one row per thread; ft16 stored padded [N][64] bf16 (zeros in pad) -----
__global__ __launch_bounds__(256) void k_gemm(const float* __restrict__ feat,
                                              const float* __restrict__ W,
                                              float* __restrict__ ft,
                                              bf16* __restrict__ ft16) {
    int row = blockIdx.x * 256 + threadIdx.x;
    if (row >= N_NODES) return;
    float acc[HD];
#pragma unroll
    for (int c = 0; c < HD; ++c) acc[c] = 0.f;
    const float4* frow = (const float4*)(feat + (size_t)row * IN_F);
    for (int k4 = 0; k4 < IN_F / 4; ++k4) {
        float4 f = frow[k4];
        int k = k4 * 4;
#pragma unroll
        for (int c = 0; c < HD; ++c) acc[c] += f.x * W[(k + 0) * HD + c];
#pragma unroll
        for (int c = 0; c < HD; ++c) acc[c] += f.y * W[(k + 1) * HD + c];
#pragma unroll
        for (int c = 0; c < HD; ++c) acc[c] += f.z * W[(k + 2) * HD + c];
#pragma unroll
        for (int c = 0; c < HD; ++c) acc[c] += f.w * W[(k + 3) * HD + c];
    }
    float4* orow = (float4*)(ft + (size_t)row * HD);
#pragma unroll
    for (int c = 0; c < HD / 4; ++c)
        orow[c] = make_float4(acc[4 * c], acc[4 * c + 1], acc[4 * c + 2], acc[4 * c + 3]);
    uint4* o16 = (uint4*)(ft16 + (size_t)row * RP);
#pragma unroll
    for (int q = 0; q < 6; ++q) {   // 6 uint4 = 48 bf16 real
        uint4 w;
        w.x = pkbf(acc[q * 8 + 0], acc[q * 8 + 1]);
        w.y = pkbf(acc[q * 8 + 2], acc[q * 8 + 3]);
        w.z = pkbf(acc[q * 8 + 4], acc[q * 8 + 5]);
        w.w = pkbf(acc[q * 8 + 6], acc[q * 8 + 7]);
        o16[q] = w;
    }
    o16[6] = make_uint4(0, 0, 0, 0);   // pad = 0.0
    o16[7] = make_uint4(0, 0, 0, 0);
}

// ---------------- el/er ----------------
__global__ void k_eler(const float* __restrict__ ft, const float* __restrict__ attn_l,
                       const float* __restrict__ attn_r, float* __restrict__ el,
                       float* __restrict__ er) {
    int i = blockIdx.x * blockDim.x + threadIdx.x;
    if (i >= N_NODES * HH) return;
    int h = i % HH;
    float sl = 0.f, sr = 0.f;
#pragma unroll
    for (int d = 0; d < DD; ++d) {
        float v = ft[i * DD + d];
        sl += v * attn_l[h * DD + d];
        sr += v * attn_r[h * DD + d];
    }
    el[i] = sl;
    er[i] = sr;
}

// ---------------- K1: per-bucket histograms (LDS-privatized, int4 loads) -------------
__global__ __launch_bounds__(256) void k_bhist(const int4* __restrict__ src4,
                                               const int4* __restrict__ dst4,
                                               int* __restrict__ bcnt_s,
                                               int* __restrict__ bcnt_d) {
    __shared__ int ls[NB], ld_[NB];
    int t = threadIdx.x;
    for (int i = t; i < NB; i += 256) { ls[i] = 0; ld_[i] = 0; }
    __syncthreads();
    const int NE4 = N_EDGES / 4;
    for (int e = blockIdx.x * 256 + t; e < NE4; e += gridDim.x * 256) {
        int4 d = dst4[e];
        atomicAdd(&ld_[d.x >> BW_SH], 1);
        atomicAdd(&ld_[d.y >> BW_SH], 1);
        atomicAdd(&ld_[d.z >> BW_SH], 1);
        atomicAdd(&ld_[d.w >> BW_SH], 1);
        int4 s = src4[e];
        atomicAdd(&ls[s.x >> BW_SH], 1);
        atomicAdd(&ls[s.y >> BW_SH], 1);
        atomicAdd(&ls[s.z >> BW_SH], 1);
        atomicAdd(&ls[s.w >> BW_SH], 1);
    }
    __syncthreads();
    for (int i = t; i < NB; i += 256) {
        if (ld_[i]) atomicAdd(&bcnt_d[i], ld_[i]);
        if (ls[i]) atomicAdd(&bcnt_s[i], ls[i]);
    }
}

// ---------------- K2: scan bucket counts -> bucket bases (+ sentinels) -------------
__global__ __launch_bounds__(512) void k_bscan(const int* __restrict__ bcnt_d,
                                               int* __restrict__ bbase_d,
                                               const int* __restrict__ bcnt_s,
                                               int* __restrict__ bbase_s,
                                               int* __restrict__ rows_d,
                                               int* __restrict__ rows_s) {
    __shared__ int buf[512];
    const int* c = blockIdx.x ? bcnt_s : bcnt_d;
    int* o = blockIdx.x ? bbase_s : bbase_d;
    int t = threadIdx.x;
    int v = (t < NB) ? c[t] : 0;
    buf[t] = v;
    __syncthreads();
    for (int off = 1; off < 512; off <<= 1) {
        int u = (t >= off) ? buf[t - off] : 0;
        __syncthreads();
        buf[t] += u;
        __syncthreads();
    }
    if (t < NB) o[t] = buf[t] - v;      // exclusive
    if (t == NB - 1) o[NB] = buf[t];    // == N_EDGES
    if (t == 0) {
        if (blockIdx.x) rows_s[N_NODES] = N_EDGES;
        else            rows_d[N_NODES] = N_EDGES;
    }
}

// ---------------- K3: multisplit — bucket edges for both directions ----------------
__global__ __launch_bounds__(256) void k_msplit(const int* __restrict__ src,
                                                const int* __restrict__ dst,
                                                const int* __restrict__ bbase_d,
                                                const int* __restrict__ bbase_s,
                                                int* __restrict__ bfill_d,
                                                int* __restrict__ bfill_s,
                                                unsigned* __restrict__ bkt_d,
                                                unsigned* __restrict__ bkt_s) {
    __shared__ int lcD[NB], lcS[NB], wbD[NB], wbS[NB], rkD[NB], rkS[NB];
    int t = threadIdx.x;
    int e0 = blockIdx.x * MS_T;
    int e1 = min(e0 + MS_T, N_EDGES);
    for (int i = t; i < NB; i += 256) { lcD[i] = 0; lcS[i] = 0; rkD[i] = 0; rkS[i] = 0; }
    __syncthreads();
    for (int e = e0 + t; e < e1; e += 256) {
        atomicAdd(&lcD[dst[e] >> BW_SH], 1);
        atomicAdd(&lcS[src[e] >> BW_SH], 1);
    }
    __syncthreads();
    for (int i = t; i < NB; i += 256) {
        wbD[i] = bbase_d[i] + (lcD[i] ? atomicAdd(&bfill_d[i], lcD[i]) : 0);
        wbS[i] = bbase_s[i] + (lcS[i] ? atomicAdd(&bfill_s[i], lcS[i]) : 0);
    }
    __syncthreads();
    for (int e = e0 + t; e < e1; e += 256) {
        int s = src[e], d = dst[e];
        int bd = d >> BW_SH, bs = s >> BW_SH;
        int rd = atomicAdd(&rkD[bd], 1);
        int rs = atomicAdd(&rkS[bs], 1);
        bkt_d[wbD[bd] + rd] = (unsigned)s | ((unsigned)(d & 255) << 17);
        bkt_s[wbS[bs] + rs] = (unsigned)d | ((unsigned)(s & 255) << 17);
    }
}

// ---------------- K4: per-bucket CSR finalize (rows + payload scatter) --------------
__global__ __launch_bounds__(256) void k_bfinal(const unsigned* __restrict__ bkt,
                                                const int* __restrict__ bbase,
                                                int* __restrict__ rows,
                                                int* __restrict__ outarr) {
    __shared__ int cnt[256], pre[256], rnk[256], wsum[4];
    int b = blockIdx.x, t = threadIdx.x;
    int base = bbase[b], end = bbase[b + 1];
    cnt[t] = 0; rnk[t] = 0;
    __syncthreads();
    for (int i = base + t; i < end; i += 256)
        atomicAdd(&cnt[(bkt[i] >> 17) & 255], 1);
    __syncthreads();
    int lane = t & 63, w = t >> 6;
    int v = cnt[t];
    int sc = v;
#pragma unroll
    for (int off = 1; off < 64; off <<= 1) {
        int u = __shfl_up(sc, off, 64);
        if (lane >= off) sc += u;
    }
    if (lane == 63) wsum[w] = sc;
    __syncthreads();
    int wpre = 0;
    for (int j = 0; j < w; ++j) wpre += wsum[j];
    int excl = wpre + sc - v;
    pre[t] = excl;
    int n = (b << BW_SH) + t;
    if (n < N_NODES) rows[n] = base + excl;
    __syncthreads();
    for (int i = base + t; i < end; i += 256) {
        unsigned u = bkt[i];
        int loc = (u >> 17) & 255;
        int r = atomicAdd(&rnk[loc], 1);
        outarr[base + pre[loc] + r] = (int)(u & 0x1FFFFu);
    }
}

// -------- src-side segment softmax stats: per-node (max, sum) only ----------
__global__ __launch_bounds__(256) void k_seg_src(const int* __restrict__ dsts_s,
                                                 const int* __restrict__ rows_s,
                                                 const float* __restrict__ el,
                                                 const float* __restrict__ er,
                                                 float2* __restrict__ mssrc) {
    int wid = threadIdx.x >> 6, lane = threadIdx.x & 63;
    int n = blockIdx.x * 4 + wid;
    if (n >= N_NODES) return;
    int rs = rows_s[n], re = rows_s[n + 1];
    if (rs >= re) return;
    float el0 = el[n * 3 + 0], el1 = el[n * 3 + 1], el2 = el[n * 3 + 2];
    bool single = (re - rs) <= 64;
    float m0 = -INFINITY, m1 = -INFINITY, m2 = -INFINITY;
    float c0 = -INFINITY, c1 = -INFINITY, c2 = -INFINITY;
    for (int p0 = rs; p0 < re; p0 += 64) {
        int p = p0 + lane;
        bool act = p < re;
        int d = act ? dsts_s[p] : 0;
        float t0 = act ? leaky(el0 + er[d * 3 + 0]) : -INFINITY;
        float t1 = act ? leaky(el1 + er[d * 3 + 1]) : -INFINITY;
        float t2 = act ? leaky(el2 + er[d * 3 + 2]) : -INFINITY;
        if (single) { c0 = t0; c1 = t1; c2 = t2; }
        m0 = fmaxf(m0, t0); m1 = fmaxf(m1, t1); m2 = fmaxf(m2, t2);
    }
#pragma unroll
    for (int off = 1; off < 64; off <<= 1) {
        m0 = fmaxf(m0, __shfl_xor(m0, off));
        m1 = fmaxf(m1, __shfl_xor(m1, off));
        m2 = fmaxf(m2, __shfl_xor(m2, off));
    }
    float s0 = 0, s1 = 0, s2 = 0;
    if (single) {
        bool act = (rs + lane) < re;
        s0 = act ? expf(c0 - m0) : 0.f;
        s1 = act ? expf(c1 - m1) : 0.f;
        s2 = act ? expf(c2 - m2) : 0.f;
    } else {
        for (int p0 = rs; p0 < re; p0 += 64) {
            int p = p0 + lane;
            if (p < re) {
                int d = dsts_s[p];
                s0 += expf(leaky(el0 + er[d * 3 + 0]) - m0);
                s1 += expf(leaky(el1 + er[d * 3 + 1]) - m1);
                s2 += expf(leaky(el2 + er[d * 3 + 2]) - m2);
            }
        }
    }
#pragma unroll
    for (int off = 1; off < 64; off <<= 1) {
        s0 += __shfl_xor(s0, off);
        s1 += __shfl_xor(s1, off);
        s2 += __shfl_xor(s2, off);
    }
    if (lane == 0) {
        mssrc[n * 3 + 0] = make_float2(m0, s0);
        mssrc[n * 3 + 1] = make_float2(m1, s1);
        mssrc[n * 3 + 2] = make_float2(m2, s2);
    }
}

// -------- dst-side stats + fused symmetric attention; a stored [E][4] bf16 ----------
__global__ __launch_bounds__(256) void k_seg_dst_attn(const int* __restrict__ srcs_d,
                                                      const int* __restrict__ rows_d,
                                                      const float* __restrict__ el,
                                                      const float* __restrict__ er,
                                                      const float2* __restrict__ mssrc,
                                                      ushort4* __restrict__ a16) {
    int wid = threadIdx.x >> 6, lane = threadIdx.x & 63;
    int n = blockIdx.x * 4 + wid;
    if (n >= N_NODES) return;
    int rs = rows_d[n], re = rows_d[n + 1];
    if (rs >= re) return;
    float er0 = er[n * 3 + 0], er1 = er[n * 3 + 1], er2 = er[n * 3 + 2];
    bool single = (re - rs) <= 64;
    float m0 = -INFINITY, m1 = -INFINITY, m2 = -INFINITY;
    float c0 = -INFINITY, c1 = -INFINITY, c2 = -INFINITY;
    int scache = 0;
    for (int p0 = rs; p0 < re; p0 += 64) {
        int p = p0 + lane;
        bool act = p < re;
        int s = act ? srcs_d[p] : 0;
        if (single) scache = s;
        float t0 = act ? leaky(el[s * 3 + 0] + er0) : -INFINITY;
        float t1 = act ? leaky(el[s * 3 + 1] + er1) : -INFINITY;
        float t2 = act ? leaky(el[s * 3 + 2] + er2) : -INFINITY;
        if (single) { c0 = t0; c1 = t1; c2 = t2; }
        m0 = fmaxf(m0, t0); m1 = fmaxf(m1, t1); m2 = fmaxf(m2, t2);
    }
#pragma unroll
    for (int off = 1; off < 64; off <<= 1) {
        m0 = fmaxf(m0, __shfl_xor(m0, off));
        m1 = fmaxf(m1, __shfl_xor(m1, off));
        m2 = fmaxf(m2, __shfl_xor(m2, off));
    }
    float s0 = 0, s1 = 0, s2 = 0;
    if (single) {
        bool act = (rs + lane) < re;
        s0 = act ? expf(c0 - m0) : 0.f;
        s1 = act ? expf(c1 - m1) : 0.f;
        s2 = act ? expf(c2 - m2) : 0.f;
    } else {
        for (int p0 = rs; p0 < re; p0 += 64) {
            int p = p0 + lane;
            if (p < re) {
                int s = srcs_d[p];
                s0 += expf(leaky(el[s * 3 + 0] + er0) - m0);
                s1 += expf(leaky(el[s * 3 + 1] + er1) - m1);
                s2 += expf(leaky(el[s * 3 + 2] + er2) - m2);
            }
        }
    }
#pragma unroll
    for (int off = 1; off < 64; off <<= 1) {
        s0 += __shfl_xor(s0, off);
        s1 += __shfl_xor(s1, off);
        s2 += __shfl_xor(s2, off);
    }
    float i0 = 1.f / s0, i1 = 1.f / s1, i2 = 1.f / s2;
    for (int p0 = rs; p0 < re; p0 += 64) {
        int p = p0 + lane;
        if (p >= re) break;
        int s = single ? scache : srcs_d[p];
        float t0, t1, t2;
        if (single) { t0 = c0; t1 = c1; t2 = c2; }
        else {
            t0 = leaky(el[s * 3 + 0] + er0);
            t1 = leaky(el[s * 3 + 1] + er1);
            t2 = leaky(el[s * 3 + 2] + er2);
        }
        float2 a0 = mssrc[s * 3 + 0], a1 = mssrc[s * 3 + 1], a2 = mssrc[s * 3 + 2];
        float d0 = fmaxf(expf(t0 - m0) * i0, EPS_V);
        float d1 = fmaxf(expf(t1 - m1) * i1, EPS_V);
        float d2 = fmaxf(expf(t2 - m2) * i2, EPS_V);
        float u0 = fmaxf(expf(t0 - a0.x) / a0.y, EPS_V);
        float u1 = fmaxf(expf(t1 - a1.x) / a1.y, EPS_V);
        float u2 = fmaxf(expf(t2 - a2.x) / a2.y, EPS_V);
        ushort4 w;
        w.x = bfbits(sqrtf(d0 * u0));
        w.y = bfbits(sqrtf(d1 * u1));
        w.z = bfbits(sqrtf(d2 * u2));
        w.w = 0;                      // pad head weight = 0 (feeds lanes 48-63)
        a16[p] = w;
    }
}

// ------- hop: wave per node, 64 lanes read one padded 128 B row; 8-deep pipeline -----
__global__ __launch_bounds__(256) void k_hop(const bf16* __restrict__ cur,
                                             const unsigned short* __restrict__ a16,
                                             const int* __restrict__ rows_d,
                                             const int* __restrict__ srcs_d,
                                             bf16* __restrict__ out) {
    int wid = threadIdx.x >> 6, lane = threadIdx.x & 63;
    int n = blockIdx.x * 4 + wid;
    if (n >= N_NODES) return;
    int h4 = lane >> 4;   // 0..3 (3 = pad head, weight 0)
    int rs = rows_d[n], re = rows_d[n + 1];
    float acc = 0.f;
    int p = rs;
    for (; p + 8 <= re; p += 8) {
        int s[8];
#pragma unroll
        for (int j = 0; j < 8; ++j) s[j] = srcs_d[p + j];
        float a[8];
#pragma unroll
        for (int j = 0; j < 8; ++j)
            a[j] = __uint_as_float(((unsigned)a16[(p + j) * 4 + h4]) << 16);
        float v[8];
#pragma unroll
        for (int j = 0; j < 8; ++j) v[j] = b2f(cur[(size_t)s[j] * RP + lane]);
#pragma unroll
        for (int j = 0; j < 8; ++j) acc += a[j] * v[j];
    }
    if (p < re) {
        int cnt = re - p;
        int s[8];
#pragma unroll
        for (int j = 0; j < 8; ++j) s[j] = (j < cnt) ? srcs_d[p + j] : 0;
        float a[8];
#pragma unroll
        for (int j = 0; j < 8; ++j)
            a[j] = (j < cnt) ? __uint_as_float(((unsigned)a16[(p + j) * 4 + h4]) << 16) : 0.f;
        float v[8];
#pragma unroll
        for (int j = 0; j < 8; ++j) v[j] = (j < cnt) ? b2f(cur[(size_t)s[j] * RP + lane]) : 0.f;
#pragma unroll
        for (int j = 0; j < 8; ++j) acc += a[j] * v[j];
    }
    out[(size_t)n * RP + lane] = __float2bfloat16(acc);   // pad lanes store 0
}

// ---------------- feat_trans + hop attention + output ----------------
__global__ void k_final(const float* __restrict__ ft, const bf16* __restrict__ cur1,
                        const bf16* __restrict__ cur2, const bf16* __restrict__ cur3,
                        const float* __restrict__ hop_l, const float* __restrict__ hop_r,
                        const float* __restrict__ pos_emb, const float* __restrict__ scales,
                        const float* __restrict__ offs, const float* __restrict__ bias,
                        float* __restrict__ out) {
    int i = blockIdx.x * blockDim.x + threadIdx.x;  // i = n*3+h
    if (i >= N_NODES * HH) return;
    int h = i % HH;
    int n = i / HH;
    size_t sl = (size_t)n * RP + h * DD;            // padded-row offset for cur*
    float hk[4][DD];
#pragma unroll
    for (int k = 0; k < 4; ++k) {
        float x[DD];
#pragma unroll
        for (int d = 0; d < DD; ++d) {
            x[d] = (k == 0) ? ft[(size_t)i * DD + d]
                 : (k == 1) ? b2f(cur1[sl + d])
                 : (k == 2) ? b2f(cur2[sl + d])
                            : b2f(cur3[sl + d]);
        }
        float m = 0.f;
#pragma unroll
        for (int d = 0; d < DD; ++d) m += x[d];
        m *= (1.f / DD);
        float v2 = 0.f;
#pragma unroll
        for (int d = 0; d < DD; ++d) {
            float c = x[d] - m;
            v2 += c * c;
        }
        v2 = v2 * (1.f / DD) + EPS_V;
        float rsq = rsqrtf(v2);
#pragma unroll
        for (int d = 0; d < DD; ++d) {
            hk[k][d] = (x[d] - m) * scales[k * HD + h * DD + d] * rsq +
                       offs[k * HD + h * DD + d] + pos_emb[h * 64 + k * DD + d];
        }
    }
    float al = 0.f;
#pragma unroll
    for (int d = 0; d < DD; ++d) al += hk[0][d] * hop_l[h * DD + d];
    float ar[3], mx = -1e30f;
#pragma unroll
    for (int k = 0; k < 3; ++k) {
        float s = 0.f;
#pragma unroll
        for (int d = 0; d < DD; ++d) s += hk[k + 1][d] * hop_r[h * DD + d];
        ar[k] = leaky(s + al);
        mx = fmaxf(mx, ar[k]);
    }
    float den = 0.f, wgt[3];
#pragma unroll
    for (int k = 0; k < 3; ++k) {
        wgt[k] = expf(ar[k] - mx);
        den += wgt[k];
    }
#pragma unroll
    for (int k = 0; k < 3; ++k) wgt[k] /= den;
#pragma unroll
    for (int d = 0; d < DD; ++d) {
        float o = hk[1][d] * wgt[0] + hk[2][d] * wgt[1] + hk[3][d] * wgt[2] +
                  bias[h * DD + d];
        out[i * DD + d] = o;
    }
}

// ---------------- workspace layout (4B-element offsets) ----------------
#define OFF_FT     0u          // 4.8M f32 [N][48]
#define OFF_FT16   4800000u    // 3.2M slots (bf16 [N][64] padded)
#define OFF_EL     8000000u    // 300k
#define OFF_ER     8300000u    // 300k
#define OFF_MSSRC  8600000u    // 600k (float2 x 300k)
#define OFF_BCNT   9200000u    // 1600 [memset]
#define OFF_BBASE  9201600u    // 800
#define OFF_ROWD   9202400u    // 100001
#define OFF_ROWS_  9302402u    // 100001
#define OFF_BKTD   9402404u    // 1.6M u32
#define OFF_BKTS   11002404u   // 1.6M u32
#define OFF_SRCSD  12602404u   // 1.6M
#define OFF_DSTSS  14202404u   // 1.6M
#define OFF_A16    15802404u   // 1.6M ushort4 = 3.2M slots ([E][4] bf16)
#define OFF_CUR1   19002404u   // 3.2M slots (bf16 [N][64])
#define OFF_CUR2   22202404u
#define OFF_CUR3   25402404u
#define WS_FLOATS  28602404u   // ~114.4 MB

extern "C" void kernel_launch(void* const* d_in, const int* in_sizes, int n_in,
                              void* d_out, int out_size, void* d_ws, size_t ws_size,
                              hipStream_t stream) {
    if (ws_size < (size_t)WS_FLOATS * 4) return;

    const float* feat   = (const float*)d_in[0];
    const int*   src    = (const int*)d_in[1];
    const int*   dst    = (const int*)d_in[2];
    const float* fc_W   = (const float*)d_in[3];
    const float* attn_l = (const float*)d_in[4];
    const float* attn_r = (const float*)d_in[5];
    const float* hop_l  = (const float*)d_in[6];
    const float* hop_r  = (const float*)d_in[7];
    const float* pos    = (const float*)d_in[8];
    const float* scal   = (const float*)d_in[9];
    const float* offs   = (const float*)d_in[10];
    const float* bias   = (const float*)d_in[11];
    float* out = (float*)d_out;

    float* ws = (float*)d_ws;
    float*          ft      = ws + OFF_FT;
    bf16*           ft16    = (bf16*)(ws + OFF_FT16);
    float*          el      = ws + OFF_EL;
    float*          er      = ws + OFF_ER;
    float2*         mssrc   = (float2*)(ws + OFF_MSSRC);
    int*            bcnt_d  = (int*)(ws + OFF_BCNT);
    int*            bcnt_s  = bcnt_d + 400;
    int*            bfill_d = bcnt_d + 800;
    int*            bfill_s = bcnt_d + 1200;
    int*            bbase_d = (int*)(ws + OFF_BBASE);
    int*            bbase_s = bbase_d + 400;
    int*            rows_d  = (int*)(ws + OFF_ROWD);
    int*            rows_s  = (int*)(ws + OFF_ROWS_);
    unsigned*       bkt_d   = (unsigned*)(ws + OFF_BKTD);
    unsigned*       bkt_s   = (unsigned*)(ws + OFF_BKTS);
    int*            srcs_d  = (int*)(ws + OFF_SRCSD);
    int*            dsts_s  = (int*)(ws + OFF_DSTSS);
    ushort4*        a16     = (ushort4*)(ws + OFF_A16);
    bf16*           cur1    = (bf16*)(ws + OFF_CUR1);
    bf16*           cur2    = (bf16*)(ws + OFF_CUR2);
    bf16*           cur3    = (bf16*)(ws + OFF_CUR3);

    hipMemsetAsync(ws + OFF_BCNT, 0, 1600 * 4, stream);

    k_gemm<<<(N_NODES + 255) / 256, 256, 0, stream>>>(feat, fc_W, ft, ft16);
    k_eler<<<(N_NODES * HH + 255) / 256, 256, 0, stream>>>(ft, attn_l, attn_r, el, er);

    k_bhist<<<400, 256, 0, stream>>>((const int4*)src, (const int4*)dst, bcnt_s, bcnt_d);
    k_bscan<<<2, 512, 0, stream>>>(bcnt_d, bbase_d, bcnt_s, bbase_s, rows_d, rows_s);
    k_msplit<<<(N_EDGES + MS_T - 1) / MS_T, 256, 0, stream>>>(src, dst, bbase_d, bbase_s,
                                                              bfill_d, bfill_s, bkt_d, bkt_s);
    k_bfinal<<<NB, 256, 0, stream>>>(bkt_d, bbase_d, rows_d, srcs_d);
    k_bfinal<<<NB, 256, 0, stream>>>(bkt_s, bbase_s, rows_s, dsts_s);

    k_seg_src<<<(N_NODES + 3) / 4, 256, 0, stream>>>(dsts_s, rows_s, el, er, mssrc);
    k_seg_dst_attn<<<(N_NODES + 3) / 4, 256, 0, stream>>>(srcs_d, rows_d, el, er,
                                                          mssrc, a16);
    k_hop<<<(N_NODES + 3) / 4, 256, 0, stream>>>(ft16, (const unsigned short*)a16,
                                                 rows_d, srcs_d, cur1);
    k_hop<<<(N_NODES + 3) / 4, 256, 0, stream>>>(cur1, (const unsigned short*)a16,
                                                 rows_d, srcs_d, cur2);
    k_hop<<<(N_NODES + 3) / 4, 256, 0, stream>>>(cur2, (const unsigned short*)a16,
                                                 rows_d, srcs_d, cur3);
    k_final<<<(N_NODES * HH + 255) / 256, 256, 0, stream>>>(ft, cur1, cur2, cur3, hop_l,
                                                            hop_r, pos, scal, offs, bias,
                                                            out);
}